// Round 4
// baseline (438.290 us; speedup 1.0000x reference)
//
#include <hip/hip_runtime.h>
#include <hip/hip_bf16.h>
#include <cfloat>

#define NROWS 4096
#define DDIM 1024
#define NT 64                    // 64x64 tiles per dimension
#define NBLK (NT * (NT + 1) / 2) // 2080 triangular blocks
#define NSLOT (NT + 1)           // 65 partial slots per column

// acc = max(acc, |x|, |y|) in one VOP3.
#define MAX3ABS(ACC, X, Y) \
    asm("v_max3_f32 %0, abs(%1), abs(%2), %0" : "+v"(ACC) : "v"(X), "v"(Y))

// lexicographic (val, idx) merge: keep smaller val, tie -> smaller idx
#define MERGE(BV, BI, V, I) \
    do { if ((V) < (BV) || ((V) == (BV) && (I) < (BI))) { BV = (V); BI = (I); } } while (0)

// ---------------------------------------------------------------------------
// Kernel 1a: per-row max + normalize into ws (fast path). One wave per row.
// ---------------------------------------------------------------------------
__global__ __launch_bounds__(256) void normalize_kernel(const float* __restrict__ feats,
                                                        const int* __restrict__ normflag,
                                                        float* __restrict__ normf) {
    const int wave = threadIdx.x >> 6;
    const int lane = threadIdx.x & 63;
    const int row  = blockIdx.x * 4 + wave;
    const float* fr = feats + (size_t)row * DDIM;
    float*       fw = normf + (size_t)row * DDIM;
    float4 v[4];
    float m = 0.0f;  // feats uniform [0,1): nonnegative
#pragma unroll
    for (int k = 0; k < 4; ++k) {
        v[k] = *(const float4*)(fr + lane * 4 + k * 256);
        m = fmaxf(fmaxf(fmaxf(m, v[k].x), fmaxf(v[k].y, v[k].z)), v[k].w);
    }
#pragma unroll
    for (int off = 32; off > 0; off >>= 1) m = fmaxf(m, __shfl_xor(m, off));
    const float r = (*normflag != 0) ? m : 1.0f;
#pragma unroll
    for (int k = 0; k < 4; ++k) {
        v[k].x /= r; v[k].y /= r; v[k].z /= r; v[k].w /= r;
        *(float4*)(fw + lane * 4 + k * 256) = v[k];
    }
}

// Kernel 1b (fallback when ws is small): per-row max only.
__global__ __launch_bounds__(256) void rowmax_kernel(const float* __restrict__ feats,
                                                     const int* __restrict__ normflag,
                                                     float* __restrict__ rowmax) {
    const int wave = threadIdx.x >> 6;
    const int lane = threadIdx.x & 63;
    const int row  = blockIdx.x * 4 + wave;
    const float* fr = feats + (size_t)row * DDIM;
    float m = 0.0f;
    for (int d = lane * 4; d < DDIM; d += 256) {
        float4 v = *(const float4*)(fr + d);
        m = fmaxf(fmaxf(fmaxf(m, v.x), fmaxf(v.y, v.z)), v.w);
    }
#pragma unroll
    for (int off = 32; off > 0; off >>= 1) m = fmaxf(m, __shfl_xor(m, off));
    if (lane == 0) rowmax[row] = (*normflag != 0) ? m : 1.0f;
}

// ---------------------------------------------------------------------------
// Kernel 2: ONE WAVE per triangular 64x64 tile block. Lanes 8x8, 8x8 elems
// per lane (rows ty8+8kk, cols tx8+8jj). LDS exactly 16 KB -> 10 blocks/CU.
// LDS intensity 1.0 elem-op/byte (vs 0.5 in the 4-wave version): the LDS pipe
// and the VALU pipe are now balanced (~170 us each, overlapped).
// Swizzle q^(row&7): A-reads 8 distinct rows per 16-lane group (row&7 = ty8)
// -> conflict-free; B-reads broadcast; staging writes 2-way (free).
// Emits argmin partials in both orientations (symmetry): slot ta for columns
// of the tb-tile, slot tb+1 for rows (=columns by symmetry) of the ta-tile.
// ---------------------------------------------------------------------------
template <bool NORM>
__global__ __launch_bounds__(64, 3) void cheb_kernel(const float* __restrict__ src,
                                                     const float* __restrict__ rowmax,
                                                     const int* __restrict__ labels,
                                                     float* __restrict__ pval,
                                                     int* __restrict__ pidx) {
    // XCD-bijective swizzle (NBLK % 8 == 0), then triangular decode.
    int bid = blockIdx.x;
    bid = (bid & 7) * (NBLK / 8) + (bid >> 3);
    float fs = sqrtf((float)((2 * NT + 1) * (2 * NT + 1) - 8 * bid));
    int ta = (int)(((float)(2 * NT + 1) - fs) * 0.5f);
    while ((ta + 1) * NT - ((ta + 1) * ta) / 2 <= bid) ++ta;      // start(ta+1) <= bid
    while (ta * NT - (ta * (ta - 1)) / 2 > bid) --ta;             // start(ta)  >  bid
    const int tb = ta + (bid - (ta * NT - (ta * (ta - 1)) / 2));
    const int iBase = ta * 64;
    const int jBase = tb * 64;

    const int lane = threadIdx.x;
    const int ty8  = lane & 7;        // row group
    const int tx8  = lane >> 3;       // col group

    __shared__ __align__(16) float As[64 * 32];
    __shared__ __align__(16) float Bs[64 * 32];

    float acc[8][8];
#pragma unroll
    for (int kk = 0; kk < 8; ++kk)
#pragma unroll
        for (int jj = 0; jj < 8; ++jj) acc[kk][jj] = 0.0f;

    // Staging: lane handles rows r0+8p (p=0..7), chunk q0. (r0+8p)&7 == r0,
    // so the swizzled float offset 4*(q0^r0) is p-invariant.
    const int r0 = lane >> 3;
    const int q0 = lane & 7;
    float* Aw = As + r0 * 32 + 4 * (q0 ^ r0);
    float* Bw = Bs + r0 * 32 + 4 * (q0 ^ r0);
    const float* gA = src + (size_t)(iBase + r0) * DDIM + 4 * q0;
    const float* gB = src + (size_t)(jBase + r0) * DDIM + 4 * q0;
    float rmA[8], rmB[8];
    if (NORM) {
#pragma unroll
        for (int p = 0; p < 8; ++p) {
            rmA[p] = rowmax[iBase + r0 + 8 * p];
            rmB[p] = rowmax[jBase + r0 + 8 * p];
        }
    }

    const char* Ab = (const char*)As + ty8 * 128;
    const char* Bb = (const char*)Bs + tx8 * 128;

    for (int dc = 0; dc < DDIM / 32; ++dc) {
        const int dB = dc * 32;
        __syncthreads();                 // LDS reuse from previous d-chunk (1 wave: cheap)
#pragma unroll 2
        for (int p = 0; p < 8; ++p) {
            float4 va = *(const float4*)(gA + (size_t)p * 8 * DDIM + dB);
            float4 vb = *(const float4*)(gB + (size_t)p * 8 * DDIM + dB);
            if (NORM) {
                va.x /= rmA[p]; va.y /= rmA[p]; va.z /= rmA[p]; va.w /= rmA[p];
                vb.x /= rmB[p]; vb.y /= rmB[p]; vb.z /= rmB[p]; vb.w /= rmB[p];
            }
            *(float4*)(Aw + p * 256) = va;
            *(float4*)(Bw + p * 256) = vb;
        }
        __syncthreads();

#pragma unroll 2
        for (int q = 0; q < 8; ++q) {
            const int oa = 16 * (q ^ ty8);
            const int ob = 16 * (q ^ tx8);
            float4 b[8];
#pragma unroll
            for (int jj = 0; jj < 8; ++jj)
                b[jj] = *(const float4*)(Bb + jj * 1024 + ob);
#pragma unroll
            for (int kk = 0; kk < 8; ++kk) {
                const float4 a = *(const float4*)(Ab + kk * 1024 + oa);
#pragma unroll
                for (int jj = 0; jj < 8; ++jj) {
                    const float d0 = a.x - b[jj].x;
                    const float d1 = a.y - b[jj].y;
                    const float d2 = a.z - b[jj].z;
                    const float d3 = a.w - b[jj].w;
                    MAX3ABS(acc[kk][jj], d0, d1);
                    MAX3ABS(acc[kk][jj], d2, d3);
                }
            }
        }
    }

    // Labels loaded after the hot loop (keeps loop register pressure down).
    int lA[8], lB[8];
#pragma unroll
    for (int kk = 0; kk < 8; ++kk) lA[kk] = labels[iBase + ty8 + 8 * kk];
#pragma unroll
    for (int jj = 0; jj < 8; ++jj) lB[jj] = labels[jBase + tx8 + 8 * jj];

    // ---- Orientation 1: per column (of tb-tile), min over this block's rows.
#pragma unroll
    for (int jj = 0; jj < 8; ++jj) {
        float bv = FLT_MAX; int bi = 0x7fffffff;
#pragma unroll
        for (int kk = 0; kk < 8; ++kk) {
            const int i = iBase + ty8 + 8 * kk;
            const float v = (lA[kk] == lB[jj]) ? FLT_MAX : acc[kk][jj];
            MERGE(bv, bi, v, i);
        }
#pragma unroll
        for (int off = 1; off <= 4; off <<= 1) {     // reduce over ty8
            const float ov = __shfl_xor(bv, off);
            const int   oi = __shfl_xor(bi, off);
            MERGE(bv, bi, ov, oi);
        }
        if (ty8 == 0) {
            const int j = jBase + tx8 + 8 * jj;
            pval[ta * NROWS + j] = bv;
            pidx[ta * NROWS + j] = bi;
        }
    }

    // ---- Orientation 2: per row (of ta-tile), min over this block's cols.
#pragma unroll
    for (int kk = 0; kk < 8; ++kk) {
        float bv = FLT_MAX; int bi = 0x7fffffff;
#pragma unroll
        for (int jj = 0; jj < 8; ++jj) {
            const int j = jBase + tx8 + 8 * jj;
            const float v = (lA[kk] == lB[jj]) ? FLT_MAX : acc[kk][jj];
            MERGE(bv, bi, v, j);
        }
#pragma unroll
        for (int off = 8; off <= 32; off <<= 1) {    // reduce over tx8
            const float ov = __shfl_xor(bv, off);
            const int   oi = __shfl_xor(bi, off);
            MERGE(bv, bi, ov, oi);
        }
        if (tx8 == 0) {
            const int i = iBase + ty8 + 8 * kk;
            pval[(tb + 1) * NROWS + i] = bv;
            pidx[(tb + 1) * NROWS + i] = bi;
        }
    }
}

// ---------------------------------------------------------------------------
// Kernel 3a: combine 65 partial slots per column; write indices + colmin.
// ---------------------------------------------------------------------------
__global__ __launch_bounds__(256) void finalizeA_kernel(const float* __restrict__ pval,
                                                        const int* __restrict__ pidx,
                                                        const int* __restrict__ image_idxs,
                                                        float* __restrict__ out,
                                                        float* __restrict__ colmin) {
    const int j = blockIdx.x * 256 + threadIdx.x;
    float bv = FLT_MAX; int bi = 0x7fffffff;
    for (int s = 0; s < NSLOT; ++s) {
        const float v = pval[s * NROWS + j];
        const int   i = pidx[s * NROWS + j];
        MERGE(bv, bi, v, i);
    }
    out[1 + j] = (float)image_idxs[bi];
    colmin[j] = bv;
}

// Kernel 3b: deterministic sum of colmin -> loss.
__global__ __launch_bounds__(256) void finalizeB_kernel(const float* __restrict__ colmin,
                                                        float* __restrict__ out) {
    const int t = threadIdx.x;
    float s = 0.0f;
#pragma unroll
    for (int k = 0; k < 16; ++k) s += colmin[t + 256 * k];
#pragma unroll
    for (int off = 32; off > 0; off >>= 1) s += __shfl_xor(s, off);
    __shared__ float ss[4];
    if ((t & 63) == 0) ss[t >> 6] = s;
    __syncthreads();
    if (t == 0) out[0] = (ss[0] + ss[1] + ss[2] + ss[3]) / (float)NROWS;
}

// ---------------------------------------------------------------------------
extern "C" void kernel_launch(void* const* d_in, const int* in_sizes, int n_in,
                              void* d_out, int out_size, void* d_ws, size_t ws_size,
                              hipStream_t stream) {
    const float* feats      = (const float*)d_in[0];
    const int*   labels     = (const int*)d_in[1];
    const int*   image_idxs = (const int*)d_in[2];
    const int*   normflag   = (const int*)d_in[3];
    float*       out        = (float*)d_out;

    const size_t normBytes = (size_t)NROWS * DDIM * sizeof(float);          // 16 MB
    const size_t partBytes = (size_t)NSLOT * NROWS * 8 + NROWS * 4;         // ~2.15 MB

    if (ws_size >= normBytes + partBytes) {
        float* normf  = (float*)d_ws;
        float* pval   = (float*)((char*)d_ws + normBytes);
        int*   pidx   = (int*)(pval + NSLOT * NROWS);
        float* colmin = (float*)(pidx + NSLOT * NROWS);
        normalize_kernel<<<NROWS / 4, 256, 0, stream>>>(feats, normflag, normf);
        cheb_kernel<false><<<NBLK, 64, 0, stream>>>(normf, nullptr, labels, pval, pidx);
        finalizeA_kernel<<<NROWS / 256, 256, 0, stream>>>(pval, pidx, image_idxs, out, colmin);
        finalizeB_kernel<<<1, 256, 0, stream>>>(colmin, out);
    } else {
        float* rowmax = (float*)d_ws;
        float* pval   = rowmax + NROWS;
        int*   pidx   = (int*)(pval + NSLOT * NROWS);
        float* colmin = (float*)(pidx + NSLOT * NROWS);
        rowmax_kernel<<<NROWS / 4, 256, 0, stream>>>(feats, normflag, rowmax);
        cheb_kernel<true><<<NBLK, 64, 0, stream>>>(feats, rowmax, labels, pval, pidx);
        finalizeA_kernel<<<NROWS / 256, 256, 0, stream>>>(pval, pidx, image_idxs, out, colmin);
        finalizeB_kernel<<<1, 256, 0, stream>>>(colmin, out);
    }
}

// Round 5
// 331.334 us; speedup vs baseline: 1.3228x; 1.3228x over previous
//
#include <hip/hip_runtime.h>
#include <hip/hip_bf16.h>
#include <cfloat>

#define NROWS 4096
#define DDIM 1024
#define NT 64                    // 64x64 tiles per dimension
#define NBLK (NT * (NT + 1) / 2) // 2080 triangular blocks
#define NSLOT (NT + 1)           // 65 partial slots per column

// acc = max(acc, |x|, |y|) in one VOP3.
#define MAX3ABS(ACC, X, Y) \
    asm("v_max3_f32 %0, abs(%1), abs(%2), %0" : "+v"(ACC) : "v"(X), "v"(Y))

// lexicographic (val, idx) merge: keep smaller val, tie -> smaller idx
#define MERGE(BV, BI, V, I) \
    do { if ((V) < (BV) || ((V) == (BV) && (I) < (BI))) { BV = (V); BI = (I); } } while (0)

// ---------------------------------------------------------------------------
// Kernel 1a: per-row max + normalize into ws (fast path). One wave per row.
// ---------------------------------------------------------------------------
__global__ __launch_bounds__(256) void normalize_kernel(const float* __restrict__ feats,
                                                        const int* __restrict__ normflag,
                                                        float* __restrict__ normf) {
    const int wave = threadIdx.x >> 6;
    const int lane = threadIdx.x & 63;
    const int row  = blockIdx.x * 4 + wave;
    const float* fr = feats + (size_t)row * DDIM;
    float*       fw = normf + (size_t)row * DDIM;
    float4 v[4];
    float m = 0.0f;  // feats uniform [0,1): nonnegative
#pragma unroll
    for (int k = 0; k < 4; ++k) {
        v[k] = *(const float4*)(fr + lane * 4 + k * 256);
        m = fmaxf(fmaxf(fmaxf(m, v[k].x), fmaxf(v[k].y, v[k].z)), v[k].w);
    }
#pragma unroll
    for (int off = 32; off > 0; off >>= 1) m = fmaxf(m, __shfl_xor(m, off));
    const float r = (*normflag != 0) ? m : 1.0f;
#pragma unroll
    for (int k = 0; k < 4; ++k) {
        v[k].x /= r; v[k].y /= r; v[k].z /= r; v[k].w /= r;
        *(float4*)(fw + lane * 4 + k * 256) = v[k];
    }
}

// Kernel 1b (fallback when ws is small): per-row max only.
__global__ __launch_bounds__(256) void rowmax_kernel(const float* __restrict__ feats,
                                                     const int* __restrict__ normflag,
                                                     float* __restrict__ rowmax) {
    const int wave = threadIdx.x >> 6;
    const int lane = threadIdx.x & 63;
    const int row  = blockIdx.x * 4 + wave;
    const float* fr = feats + (size_t)row * DDIM;
    float m = 0.0f;
    for (int d = lane * 4; d < DDIM; d += 256) {
        float4 v = *(const float4*)(fr + d);
        m = fmaxf(fmaxf(fmaxf(m, v.x), fmaxf(v.y, v.z)), v.w);
    }
#pragma unroll
    for (int off = 32; off > 0; off >>= 1) m = fmaxf(m, __shfl_xor(m, off));
    if (lane == 0) rowmax[row] = (*normflag != 0) ? m : 1.0f;
}

// ---------------------------------------------------------------------------
// Kernel 2: 256 threads (4 waves) per triangular 64x64 tile block.
// All 4 waves hold a FULL 8x8-per-lane accumulator over the same 64x64 tile,
// split by q: wave w processes q in {2w, 2w+1} of each staged 32-float
// d-chunk. LDS intensity 1.0 elem-op/byte; VALU and LDS pipes both ~166 us,
// overlapped. launch_bounds(256,2) -> 256-VGPR budget so acc stays in arch
// VGPRs (round-4 lesson: a 170 budget homed acc in AGPRs -> 2.2x VALU from
// v_accvgpr shuttles around the inline-asm max3).
// Swizzle q^(row&7): A-reads 8 distinct rows per 16-lane group -> conflict-
// free; B-reads broadcast; staging writes 2-way (free).
// End: 3-step LDS tree max-merge of the 4 q-partials into wave 0 (reusing the
// 16 KB As/Bs buffer), then wave 0 emits argmin partials in both orientations.
// ---------------------------------------------------------------------------
template <bool NORM>
__global__ __launch_bounds__(256, 2) void cheb_kernel(const float* __restrict__ src,
                                                      const float* __restrict__ rowmax,
                                                      const int* __restrict__ labels,
                                                      float* __restrict__ pval,
                                                      int* __restrict__ pidx) {
    // XCD-bijective swizzle (NBLK % 8 == 0), then triangular decode.
    int bid = blockIdx.x;
    bid = (bid & 7) * (NBLK / 8) + (bid >> 3);
    float fs = sqrtf((float)((2 * NT + 1) * (2 * NT + 1) - 8 * bid));
    int ta = (int)(((float)(2 * NT + 1) - fs) * 0.5f);
    while ((ta + 1) * NT - ((ta + 1) * ta) / 2 <= bid) ++ta;      // start(ta+1) <= bid
    while (ta * NT - (ta * (ta - 1)) / 2 > bid) --ta;             // start(ta)  >  bid
    const int tb = ta + (bid - (ta * NT - (ta * (ta - 1)) / 2));
    const int iBase = ta * 64;
    const int jBase = tb * 64;

    const int t    = threadIdx.x;
    const int w    = t >> 6;          // wave 0..3 (q-slice owner)
    const int lane = t & 63;
    const int ty8  = lane & 7;        // row group
    const int tx8  = lane >> 3;       // col group

    __shared__ __align__(16) float lds[4096];   // 16 KB: As | Bs, reused as merge buf
    float* As = lds;
    float* Bs = lds + 2048;

    float acc[8][8];
#pragma unroll
    for (int kk = 0; kk < 8; ++kk)
#pragma unroll
        for (int jj = 0; jj < 8; ++jj) acc[kk][jj] = 0.0f;

    // Staging: thread handles rows r0 and r0+32, chunk q0, for both A and B.
    // (r0+32)&7 == r0&7, so the swizzled offset is shared.
    const int r0  = t >> 3;           // 0..31
    const int q0  = t & 7;
    const int swz = 4 * (q0 ^ (r0 & 7));
    float* Aw0 = As + r0 * 32 + swz;
    float* Aw1 = As + (r0 + 32) * 32 + swz;
    float* Bw0 = Bs + r0 * 32 + swz;
    float* Bw1 = Bs + (r0 + 32) * 32 + swz;
    const float* gA0 = src + (size_t)(iBase + r0) * DDIM + 4 * q0;
    const float* gA1 = src + (size_t)(iBase + r0 + 32) * DDIM + 4 * q0;
    const float* gB0 = src + (size_t)(jBase + r0) * DDIM + 4 * q0;
    const float* gB1 = src + (size_t)(jBase + r0 + 32) * DDIM + 4 * q0;
    float rA0 = 1.0f, rA1 = 1.0f, rB0 = 1.0f, rB1 = 1.0f;
    if (NORM) {
        rA0 = rowmax[iBase + r0]; rA1 = rowmax[iBase + r0 + 32];
        rB0 = rowmax[jBase + r0]; rB1 = rowmax[jBase + r0 + 32];
    }

    const char* Ab = (const char*)As + ty8 * 128;
    const char* Bb = (const char*)Bs + tx8 * 128;

    // Register prefetch of chunk 0.
    float4 pa0 = *(const float4*)(gA0);
    float4 pa1 = *(const float4*)(gA1);
    float4 pb0 = *(const float4*)(gB0);
    float4 pb1 = *(const float4*)(gB1);

    for (int dc = 0; dc < DDIM / 32; ++dc) {
        __syncthreads();                 // previous chunk's reads complete
        if (NORM) {
            pa0.x /= rA0; pa0.y /= rA0; pa0.z /= rA0; pa0.w /= rA0;
            pa1.x /= rA1; pa1.y /= rA1; pa1.z /= rA1; pa1.w /= rA1;
            pb0.x /= rB0; pb0.y /= rB0; pb0.z /= rB0; pb0.w /= rB0;
            pb1.x /= rB1; pb1.y /= rB1; pb1.z /= rB1; pb1.w /= rB1;
        }
        *(float4*)Aw0 = pa0;
        *(float4*)Aw1 = pa1;
        *(float4*)Bw0 = pb0;
        *(float4*)Bw1 = pb1;
        __syncthreads();

        if (dc + 1 < DDIM / 32) {        // prefetch next chunk; hides under compute
            const int dB = (dc + 1) * 32;
            pa0 = *(const float4*)(gA0 + dB);
            pa1 = *(const float4*)(gA1 + dB);
            pb0 = *(const float4*)(gB0 + dB);
            pb1 = *(const float4*)(gB1 + dB);
        }

#pragma unroll
        for (int qi = 0; qi < 2; ++qi) {
            const int q  = 2 * w + qi;
            const int oa = 16 * (q ^ ty8);
            const int ob = 16 * (q ^ tx8);
            float4 b[8];
#pragma unroll
            for (int jj = 0; jj < 8; ++jj)
                b[jj] = *(const float4*)(Bb + jj * 1024 + ob);
#pragma unroll
            for (int kk = 0; kk < 8; ++kk) {
                const float4 a = *(const float4*)(Ab + kk * 1024 + oa);
#pragma unroll
                for (int jj = 0; jj < 8; ++jj) {
                    const float d0 = a.x - b[jj].x;
                    const float d1 = a.y - b[jj].y;
                    const float d2 = a.z - b[jj].z;
                    const float d3 = a.w - b[jj].w;
                    MAX3ABS(acc[kk][jj], d0, d1);
                    MAX3ABS(acc[kk][jj], d2, d3);
                }
            }
        }
    }

    // Labels (only wave 0 needs them) issued early to hide latency under merge.
    int lA[8], lB[8];
    if (w == 0) {
#pragma unroll
        for (int kk = 0; kk < 8; ++kk) lA[kk] = labels[iBase + ty8 + 8 * kk];
#pragma unroll
        for (int jj = 0; jj < 8; ++jj) lB[jj] = labels[jBase + tx8 + 8 * jj];
    }

    // ---- Tree max-merge of the 4 q-partial accumulators into wave 0. ----
    // mbuf layout: lane L, float4-group g at float index L*64 + 4*(g^(L&15)).
    // 16-lane group: quad (g^L)&7 -> 8 distinct quads, 2 lanes each (free).
    float* mbuf = lds;                   // As/Bs are dead now
    __syncthreads();
#define WRITE_ACC() do {                                                     \
    _Pragma("unroll")                                                        \
    for (int g = 0; g < 16; ++g) {                                           \
        float4 v;                                                            \
        v.x = acc[g >> 1][(g & 1) * 4 + 0]; v.y = acc[g >> 1][(g & 1) * 4 + 1]; \
        v.z = acc[g >> 1][(g & 1) * 4 + 2]; v.w = acc[g >> 1][(g & 1) * 4 + 3]; \
        *(float4*)(mbuf + lane * 64 + 4 * (g ^ (lane & 15))) = v;            \
    } } while (0)
#define MERGE_ACC() do {                                                     \
    _Pragma("unroll")                                                        \
    for (int g = 0; g < 16; ++g) {                                           \
        float4 v = *(const float4*)(mbuf + lane * 64 + 4 * (g ^ (lane & 15))); \
        acc[g >> 1][(g & 1) * 4 + 0] = fmaxf(acc[g >> 1][(g & 1) * 4 + 0], v.x); \
        acc[g >> 1][(g & 1) * 4 + 1] = fmaxf(acc[g >> 1][(g & 1) * 4 + 1], v.y); \
        acc[g >> 1][(g & 1) * 4 + 2] = fmaxf(acc[g >> 1][(g & 1) * 4 + 2], v.z); \
        acc[g >> 1][(g & 1) * 4 + 3] = fmaxf(acc[g >> 1][(g & 1) * 4 + 3], v.w); \
    } } while (0)
    if (w == 2) WRITE_ACC();
    __syncthreads();
    if (w == 0) MERGE_ACC();
    __syncthreads();
    if (w == 3) WRITE_ACC();
    __syncthreads();
    if (w == 1) { MERGE_ACC(); WRITE_ACC(); }   // same-lane read->write, no race
    __syncthreads();
    if (w == 0) MERGE_ACC();

    if (w == 0) {
        // ---- Orientation 1: per column (tb-tile), min over this block's rows.
#pragma unroll
        for (int jj = 0; jj < 8; ++jj) {
            float bv = FLT_MAX; int bi = 0x7fffffff;
#pragma unroll
            for (int kk = 0; kk < 8; ++kk) {
                const int i = iBase + ty8 + 8 * kk;
                const float v = (lA[kk] == lB[jj]) ? FLT_MAX : acc[kk][jj];
                MERGE(bv, bi, v, i);
            }
#pragma unroll
            for (int off = 1; off <= 4; off <<= 1) {     // reduce over ty8
                const float ov = __shfl_xor(bv, off);
                const int   oi = __shfl_xor(bi, off);
                MERGE(bv, bi, ov, oi);
            }
            if (ty8 == 0) {
                const int j = jBase + tx8 + 8 * jj;
                pval[ta * NROWS + j] = bv;
                pidx[ta * NROWS + j] = bi;
            }
        }
        // ---- Orientation 2: per row (ta-tile), min over this block's cols.
#pragma unroll
        for (int kk = 0; kk < 8; ++kk) {
            float bv = FLT_MAX; int bi = 0x7fffffff;
#pragma unroll
            for (int jj = 0; jj < 8; ++jj) {
                const int j = jBase + tx8 + 8 * jj;
                const float v = (lA[kk] == lB[jj]) ? FLT_MAX : acc[kk][jj];
                MERGE(bv, bi, v, j);
            }
#pragma unroll
            for (int off = 8; off <= 32; off <<= 1) {    // reduce over tx8
                const float ov = __shfl_xor(bv, off);
                const int   oi = __shfl_xor(bi, off);
                MERGE(bv, bi, ov, oi);
            }
            if (tx8 == 0) {
                const int i = iBase + ty8 + 8 * kk;
                pval[(tb + 1) * NROWS + i] = bv;
                pidx[(tb + 1) * NROWS + i] = bi;
            }
        }
    }
}

// ---------------------------------------------------------------------------
// Kernel 3a: combine 65 partial slots per column; write indices + colmin.
// ---------------------------------------------------------------------------
__global__ __launch_bounds__(256) void finalizeA_kernel(const float* __restrict__ pval,
                                                        const int* __restrict__ pidx,
                                                        const int* __restrict__ image_idxs,
                                                        float* __restrict__ out,
                                                        float* __restrict__ colmin) {
    const int j = blockIdx.x * 256 + threadIdx.x;
    float bv = FLT_MAX; int bi = 0x7fffffff;
    for (int s = 0; s < NSLOT; ++s) {
        const float v = pval[s * NROWS + j];
        const int   i = pidx[s * NROWS + j];
        MERGE(bv, bi, v, i);
    }
    out[1 + j] = (float)image_idxs[bi];
    colmin[j] = bv;
}

// Kernel 3b: deterministic sum of colmin -> loss.
__global__ __launch_bounds__(256) void finalizeB_kernel(const float* __restrict__ colmin,
                                                        float* __restrict__ out) {
    const int t = threadIdx.x;
    float s = 0.0f;
#pragma unroll
    for (int k = 0; k < 16; ++k) s += colmin[t + 256 * k];
#pragma unroll
    for (int off = 32; off > 0; off >>= 1) s += __shfl_xor(s, off);
    __shared__ float ss[4];
    if ((t & 63) == 0) ss[t >> 6] = s;
    __syncthreads();
    if (t == 0) out[0] = (ss[0] + ss[1] + ss[2] + ss[3]) / (float)NROWS;
}

// ---------------------------------------------------------------------------
extern "C" void kernel_launch(void* const* d_in, const int* in_sizes, int n_in,
                              void* d_out, int out_size, void* d_ws, size_t ws_size,
                              hipStream_t stream) {
    const float* feats      = (const float*)d_in[0];
    const int*   labels     = (const int*)d_in[1];
    const int*   image_idxs = (const int*)d_in[2];
    const int*   normflag   = (const int*)d_in[3];
    float*       out        = (float*)d_out;

    const size_t normBytes = (size_t)NROWS * DDIM * sizeof(float);          // 16 MB
    const size_t partBytes = (size_t)NSLOT * NROWS * 8 + NROWS * 4;         // ~2.15 MB

    if (ws_size >= normBytes + partBytes) {
        float* normf  = (float*)d_ws;
        float* pval   = (float*)((char*)d_ws + normBytes);
        int*   pidx   = (int*)(pval + NSLOT * NROWS);
        float* colmin = (float*)(pidx + NSLOT * NROWS);
        normalize_kernel<<<NROWS / 4, 256, 0, stream>>>(feats, normflag, normf);
        cheb_kernel<false><<<NBLK, 256, 0, stream>>>(normf, nullptr, labels, pval, pidx);
        finalizeA_kernel<<<NROWS / 256, 256, 0, stream>>>(pval, pidx, image_idxs, out, colmin);
        finalizeB_kernel<<<1, 256, 0, stream>>>(colmin, out);
    } else {
        float* rowmax = (float*)d_ws;
        float* pval   = rowmax + NROWS;
        int*   pidx   = (int*)(pval + NSLOT * NROWS);
        float* colmin = (float*)(pidx + NSLOT * NROWS);
        rowmax_kernel<<<NROWS / 4, 256, 0, stream>>>(feats, normflag, rowmax);
        cheb_kernel<true><<<NBLK, 256, 0, stream>>>(feats, rowmax, labels, pval, pidx);
        finalizeA_kernel<<<NROWS / 256, 256, 0, stream>>>(pval, pidx, image_idxs, out, colmin);
        finalizeB_kernel<<<1, 256, 0, stream>>>(colmin, out);
    }
}

// Round 6
// 330.837 us; speedup vs baseline: 1.3248x; 1.0015x over previous
//
#include <hip/hip_runtime.h>
#include <hip/hip_bf16.h>
#include <cfloat>

#define NROWS 4096
#define DDIM 1024
#define NT 64                    // 64x64 tiles per dimension
#define NBLK (NT * (NT + 1) / 2) // 2080 triangular blocks
#define NSLOT (NT + 1)           // 65 partial slots per column

// acc = max(acc, |x|, |y|). Plain fmaxf chain: LLVM's canonical v_max3_f32
// combine, with |.| folded as VOP3 source modifiers. NO inline asm: the
// round-4/5 lesson is that a "+v" asm constraint forces v_accvgpr_read/write
// shuttles whenever the allocator homes acc in AGPRs (unified file), costing
// ~2x VALU. Compiler-emitted max3 operates on AGPRs directly on CDNA4.
#define MAX3ABS(ACC, X, Y) (ACC) = fmaxf(fmaxf(fabsf(X), fabsf(Y)), (ACC))

// lexicographic (val, idx) merge: keep smaller val, tie -> smaller idx
#define MERGE(BV, BI, V, I) \
    do { if ((V) < (BV) || ((V) == (BV) && (I) < (BI))) { BV = (V); BI = (I); } } while (0)

// ---------------------------------------------------------------------------
// Kernel 1a: per-row max + normalize into ws (fast path). One wave per row.
// ---------------------------------------------------------------------------
__global__ __launch_bounds__(256) void normalize_kernel(const float* __restrict__ feats,
                                                        const int* __restrict__ normflag,
                                                        float* __restrict__ normf) {
    const int wave = threadIdx.x >> 6;
    const int lane = threadIdx.x & 63;
    const int row  = blockIdx.x * 4 + wave;
    const float* fr = feats + (size_t)row * DDIM;
    float*       fw = normf + (size_t)row * DDIM;
    float4 v[4];
    float m = 0.0f;  // feats uniform [0,1): nonnegative
#pragma unroll
    for (int k = 0; k < 4; ++k) {
        v[k] = *(const float4*)(fr + lane * 4 + k * 256);
        m = fmaxf(fmaxf(fmaxf(m, v[k].x), fmaxf(v[k].y, v[k].z)), v[k].w);
    }
#pragma unroll
    for (int off = 32; off > 0; off >>= 1) m = fmaxf(m, __shfl_xor(m, off));
    const float r = (*normflag != 0) ? m : 1.0f;
#pragma unroll
    for (int k = 0; k < 4; ++k) {
        v[k].x /= r; v[k].y /= r; v[k].z /= r; v[k].w /= r;
        *(float4*)(fw + lane * 4 + k * 256) = v[k];
    }
}

// Kernel 1b (fallback when ws is small): per-row max only.
__global__ __launch_bounds__(256) void rowmax_kernel(const float* __restrict__ feats,
                                                     const int* __restrict__ normflag,
                                                     float* __restrict__ rowmax) {
    const int wave = threadIdx.x >> 6;
    const int lane = threadIdx.x & 63;
    const int row  = blockIdx.x * 4 + wave;
    const float* fr = feats + (size_t)row * DDIM;
    float m = 0.0f;
    for (int d = lane * 4; d < DDIM; d += 256) {
        float4 v = *(const float4*)(fr + d);
        m = fmaxf(fmaxf(fmaxf(m, v.x), fmaxf(v.y, v.z)), v.w);
    }
#pragma unroll
    for (int off = 32; off > 0; off >>= 1) m = fmaxf(m, __shfl_xor(m, off));
    if (lane == 0) rowmax[row] = (*normflag != 0) ? m : 1.0f;
}

// ---------------------------------------------------------------------------
// Kernel 2: 256 threads (4 waves) per triangular 64x64 tile block.
// All 4 waves hold a FULL 8x8-per-lane accumulator over the same 64x64 tile,
// split by q: wave w processes q in {2w, 2w+1} of each staged 32-float
// d-chunk. LDS intensity 1.0 elem-op/byte; VALU and LDS pipes overlapped.
// Swizzle q^(row&7): A-reads 8 distinct rows per 16-lane group -> conflict-
// free; B-reads broadcast; staging writes 2-way (free).
// End: 3-step LDS tree max-merge of the 4 q-partials into wave 0 (reusing the
// 16 KB As/Bs buffer), then wave 0 emits argmin partials in both orientations.
// ---------------------------------------------------------------------------
template <bool NORM>
__global__ __launch_bounds__(256, 2) void cheb_kernel(const float* __restrict__ src,
                                                      const float* __restrict__ rowmax,
                                                      const int* __restrict__ labels,
                                                      float* __restrict__ pval,
                                                      int* __restrict__ pidx) {
    // XCD-bijective swizzle (NBLK % 8 == 0), then triangular decode.
    int bid = blockIdx.x;
    bid = (bid & 7) * (NBLK / 8) + (bid >> 3);
    float fs = sqrtf((float)((2 * NT + 1) * (2 * NT + 1) - 8 * bid));
    int ta = (int)(((float)(2 * NT + 1) - fs) * 0.5f);
    while ((ta + 1) * NT - ((ta + 1) * ta) / 2 <= bid) ++ta;      // start(ta+1) <= bid
    while (ta * NT - (ta * (ta - 1)) / 2 > bid) --ta;             // start(ta)  >  bid
    const int tb = ta + (bid - (ta * NT - (ta * (ta - 1)) / 2));
    const int iBase = ta * 64;
    const int jBase = tb * 64;

    const int t    = threadIdx.x;
    const int w    = t >> 6;          // wave 0..3 (q-slice owner)
    const int lane = t & 63;
    const int ty8  = lane & 7;        // row group
    const int tx8  = lane >> 3;       // col group

    __shared__ __align__(16) float lds[4096];   // 16 KB: As | Bs, reused as merge buf
    float* As = lds;
    float* Bs = lds + 2048;

    float acc[8][8];
#pragma unroll
    for (int kk = 0; kk < 8; ++kk)
#pragma unroll
        for (int jj = 0; jj < 8; ++jj) acc[kk][jj] = 0.0f;

    // Staging: thread handles rows r0 and r0+32, chunk q0, for both A and B.
    // (r0+32)&7 == r0&7, so the swizzled offset is shared.
    const int r0  = t >> 3;           // 0..31
    const int q0  = t & 7;
    const int swz = 4 * (q0 ^ (r0 & 7));
    float* Aw0 = As + r0 * 32 + swz;
    float* Aw1 = As + (r0 + 32) * 32 + swz;
    float* Bw0 = Bs + r0 * 32 + swz;
    float* Bw1 = Bs + (r0 + 32) * 32 + swz;
    const float* gA0 = src + (size_t)(iBase + r0) * DDIM + 4 * q0;
    const float* gA1 = src + (size_t)(iBase + r0 + 32) * DDIM + 4 * q0;
    const float* gB0 = src + (size_t)(jBase + r0) * DDIM + 4 * q0;
    const float* gB1 = src + (size_t)(jBase + r0 + 32) * DDIM + 4 * q0;
    float rA0 = 1.0f, rA1 = 1.0f, rB0 = 1.0f, rB1 = 1.0f;
    if (NORM) {
        rA0 = rowmax[iBase + r0]; rA1 = rowmax[iBase + r0 + 32];
        rB0 = rowmax[jBase + r0]; rB1 = rowmax[jBase + r0 + 32];
    }

    const char* Ab = (const char*)As + ty8 * 128;
    const char* Bb = (const char*)Bs + tx8 * 128;

    // Register prefetch of chunk 0.
    float4 pa0 = *(const float4*)(gA0);
    float4 pa1 = *(const float4*)(gA1);
    float4 pb0 = *(const float4*)(gB0);
    float4 pb1 = *(const float4*)(gB1);

    for (int dc = 0; dc < DDIM / 32; ++dc) {
        __syncthreads();                 // previous chunk's reads complete
        if (NORM) {
            pa0.x /= rA0; pa0.y /= rA0; pa0.z /= rA0; pa0.w /= rA0;
            pa1.x /= rA1; pa1.y /= rA1; pa1.z /= rA1; pa1.w /= rA1;
            pb0.x /= rB0; pb0.y /= rB0; pb0.z /= rB0; pb0.w /= rB0;
            pb1.x /= rB1; pb1.y /= rB1; pb1.z /= rB1; pb1.w /= rB1;
        }
        *(float4*)Aw0 = pa0;
        *(float4*)Aw1 = pa1;
        *(float4*)Bw0 = pb0;
        *(float4*)Bw1 = pb1;
        __syncthreads();

        if (dc + 1 < DDIM / 32) {        // prefetch next chunk; hides under compute
            const int dB = (dc + 1) * 32;
            pa0 = *(const float4*)(gA0 + dB);
            pa1 = *(const float4*)(gA1 + dB);
            pb0 = *(const float4*)(gB0 + dB);
            pb1 = *(const float4*)(gB1 + dB);
        }

#pragma unroll
        for (int qi = 0; qi < 2; ++qi) {
            const int q  = 2 * w + qi;
            const int oa = 16 * (q ^ ty8);
            const int ob = 16 * (q ^ tx8);
            float4 b[8];
#pragma unroll
            for (int jj = 0; jj < 8; ++jj)
                b[jj] = *(const float4*)(Bb + jj * 1024 + ob);
#pragma unroll
            for (int kk = 0; kk < 8; ++kk) {
                const float4 a = *(const float4*)(Ab + kk * 1024 + oa);
#pragma unroll
                for (int jj = 0; jj < 8; ++jj) {
                    const float d0 = a.x - b[jj].x;
                    const float d1 = a.y - b[jj].y;
                    const float d2 = a.z - b[jj].z;
                    const float d3 = a.w - b[jj].w;
                    MAX3ABS(acc[kk][jj], d0, d1);
                    MAX3ABS(acc[kk][jj], d2, d3);
                }
            }
        }
    }

    // Labels (only wave 0 needs them) issued early to hide latency under merge.
    int lA[8], lB[8];
    if (w == 0) {
#pragma unroll
        for (int kk = 0; kk < 8; ++kk) lA[kk] = labels[iBase + ty8 + 8 * kk];
#pragma unroll
        for (int jj = 0; jj < 8; ++jj) lB[jj] = labels[jBase + tx8 + 8 * jj];
    }

    // ---- Tree max-merge of the 4 q-partial accumulators into wave 0. ----
    // mbuf layout: lane L, float4-group g at float index L*64 + 4*(g^(L&15)).
    // 16-lane group: quad (g^L)&7 -> 8 distinct quads, 2 lanes each (free).
    float* mbuf = lds;                   // As/Bs are dead now
    __syncthreads();
#define WRITE_ACC() do {                                                     \
    _Pragma("unroll")                                                        \
    for (int g = 0; g < 16; ++g) {                                           \
        float4 v;                                                            \
        v.x = acc[g >> 1][(g & 1) * 4 + 0]; v.y = acc[g >> 1][(g & 1) * 4 + 1]; \
        v.z = acc[g >> 1][(g & 1) * 4 + 2]; v.w = acc[g >> 1][(g & 1) * 4 + 3]; \
        *(float4*)(mbuf + lane * 64 + 4 * (g ^ (lane & 15))) = v;            \
    } } while (0)
#define MERGE_ACC() do {                                                     \
    _Pragma("unroll")                                                        \
    for (int g = 0; g < 16; ++g) {                                           \
        float4 v = *(const float4*)(mbuf + lane * 64 + 4 * (g ^ (lane & 15))); \
        acc[g >> 1][(g & 1) * 4 + 0] = fmaxf(acc[g >> 1][(g & 1) * 4 + 0], v.x); \
        acc[g >> 1][(g & 1) * 4 + 1] = fmaxf(acc[g >> 1][(g & 1) * 4 + 1], v.y); \
        acc[g >> 1][(g & 1) * 4 + 2] = fmaxf(acc[g >> 1][(g & 1) * 4 + 2], v.z); \
        acc[g >> 1][(g & 1) * 4 + 3] = fmaxf(acc[g >> 1][(g & 1) * 4 + 3], v.w); \
    } } while (0)
    if (w == 2) WRITE_ACC();
    __syncthreads();
    if (w == 0) MERGE_ACC();
    __syncthreads();
    if (w == 3) WRITE_ACC();
    __syncthreads();
    if (w == 1) { MERGE_ACC(); WRITE_ACC(); }   // same-lane read->write, no race
    __syncthreads();
    if (w == 0) MERGE_ACC();

    if (w == 0) {
        // ---- Orientation 1: per column (tb-tile), min over this block's rows.
#pragma unroll
        for (int jj = 0; jj < 8; ++jj) {
            float bv = FLT_MAX; int bi = 0x7fffffff;
#pragma unroll
            for (int kk = 0; kk < 8; ++kk) {
                const int i = iBase + ty8 + 8 * kk;
                const float v = (lA[kk] == lB[jj]) ? FLT_MAX : acc[kk][jj];
                MERGE(bv, bi, v, i);
            }
#pragma unroll
            for (int off = 1; off <= 4; off <<= 1) {     // reduce over ty8
                const float ov = __shfl_xor(bv, off);
                const int   oi = __shfl_xor(bi, off);
                MERGE(bv, bi, ov, oi);
            }
            if (ty8 == 0) {
                const int j = jBase + tx8 + 8 * jj;
                pval[ta * NROWS + j] = bv;
                pidx[ta * NROWS + j] = bi;
            }
        }
        // ---- Orientation 2: per row (ta-tile), min over this block's cols.
#pragma unroll
        for (int kk = 0; kk < 8; ++kk) {
            float bv = FLT_MAX; int bi = 0x7fffffff;
#pragma unroll
            for (int jj = 0; jj < 8; ++jj) {
                const int j = jBase + tx8 + 8 * jj;
                const float v = (lA[kk] == lB[jj]) ? FLT_MAX : acc[kk][jj];
                MERGE(bv, bi, v, j);
            }
#pragma unroll
            for (int off = 8; off <= 32; off <<= 1) {    // reduce over tx8
                const float ov = __shfl_xor(bv, off);
                const int   oi = __shfl_xor(bi, off);
                MERGE(bv, bi, ov, oi);
            }
            if (tx8 == 0) {
                const int i = iBase + ty8 + 8 * kk;
                pval[(tb + 1) * NROWS + i] = bv;
                pidx[(tb + 1) * NROWS + i] = bi;
            }
        }
    }
}

// ---------------------------------------------------------------------------
// Kernel 3a: combine 65 partial slots per column; write indices + colmin.
// ---------------------------------------------------------------------------
__global__ __launch_bounds__(256) void finalizeA_kernel(const float* __restrict__ pval,
                                                        const int* __restrict__ pidx,
                                                        const int* __restrict__ image_idxs,
                                                        float* __restrict__ out,
                                                        float* __restrict__ colmin) {
    const int j = blockIdx.x * 256 + threadIdx.x;
    float bv = FLT_MAX; int bi = 0x7fffffff;
    for (int s = 0; s < NSLOT; ++s) {
        const float v = pval[s * NROWS + j];
        const int   i = pidx[s * NROWS + j];
        MERGE(bv, bi, v, i);
    }
    out[1 + j] = (float)image_idxs[bi];
    colmin[j] = bv;
}

// Kernel 3b: deterministic sum of colmin -> loss.
__global__ __launch_bounds__(256) void finalizeB_kernel(const float* __restrict__ colmin,
                                                        float* __restrict__ out) {
    const int t = threadIdx.x;
    float s = 0.0f;
#pragma unroll
    for (int k = 0; k < 16; ++k) s += colmin[t + 256 * k];
#pragma unroll
    for (int off = 32; off > 0; off >>= 1) s += __shfl_xor(s, off);
    __shared__ float ss[4];
    if ((t & 63) == 0) ss[t >> 6] = s;
    __syncthreads();
    if (t == 0) out[0] = (ss[0] + ss[1] + ss[2] + ss[3]) / (float)NROWS;
}

// ---------------------------------------------------------------------------
extern "C" void kernel_launch(void* const* d_in, const int* in_sizes, int n_in,
                              void* d_out, int out_size, void* d_ws, size_t ws_size,
                              hipStream_t stream) {
    const float* feats      = (const float*)d_in[0];
    const int*   labels     = (const int*)d_in[1];
    const int*   image_idxs = (const int*)d_in[2];
    const int*   normflag   = (const int*)d_in[3];
    float*       out        = (float*)d_out;

    const size_t normBytes = (size_t)NROWS * DDIM * sizeof(float);          // 16 MB
    const size_t partBytes = (size_t)NSLOT * NROWS * 8 + NROWS * 4;         // ~2.15 MB

    if (ws_size >= normBytes + partBytes) {
        float* normf  = (float*)d_ws;
        float* pval   = (float*)((char*)d_ws + normBytes);
        int*   pidx   = (int*)(pval + NSLOT * NROWS);
        float* colmin = (float*)(pidx + NSLOT * NROWS);
        normalize_kernel<<<NROWS / 4, 256, 0, stream>>>(feats, normflag, normf);
        cheb_kernel<false><<<NBLK, 256, 0, stream>>>(normf, nullptr, labels, pval, pidx);
        finalizeA_kernel<<<NROWS / 256, 256, 0, stream>>>(pval, pidx, image_idxs, out, colmin);
        finalizeB_kernel<<<1, 256, 0, stream>>>(colmin, out);
    } else {
        float* rowmax = (float*)d_ws;
        float* pval   = rowmax + NROWS;
        int*   pidx   = (int*)(pval + NSLOT * NROWS);
        float* colmin = (float*)(pidx + NSLOT * NROWS);
        rowmax_kernel<<<NROWS / 4, 256, 0, stream>>>(feats, normflag, rowmax);
        cheb_kernel<true><<<NBLK, 256, 0, stream>>>(feats, rowmax, labels, pval, pidx);
        finalizeA_kernel<<<NROWS / 256, 256, 0, stream>>>(pval, pidx, image_idxs, out, colmin);
        finalizeB_kernel<<<1, 256, 0, stream>>>(colmin, out);
    }
}